// Round 13
// baseline (46983.771 us; speedup 1.0000x reference)
//
#include <hip/hip_runtime.h>
#include <cmath>

typedef __attribute__((ext_vector_type(8))) short short8;
typedef __attribute__((ext_vector_type(4))) float f32x4;

#define B_SZ 512
#define T_SZ 256
#define I_SZ 256
#define H_SZ 1024
#define V_SZ 1024
#define E_SZ 8
#define FUT 64

// R5 numerics (3 products: A_hi*W_hi + A_hi*W_lo + A_lo*W_hi), paired layout
// (R12, verified). A phys:
//   enc: [x_hi 256 | x_lo 256 | h_hi 1024 | h_lo 1024] = 2560
//   dec: [xc 128 (x_hi8|x_hi8|x_lo8|0) | h_hi 1024 | h_lo 1024] = 2176
// W packed: paired region [W_hi(seg)|W_lo(seg)] ×128, then singles [W_hi] ×64.
#define KVE 3840
#define KVD 3200
#define KVF 3072
#define APE 2560
#define APD 2176

#define NBLK 512   // persistent grid: 2 blocks/CU on 256 CUs

struct GBar { unsigned int cnt; unsigned int gen; };

static __device__ __forceinline__ ushort f2bf(float v) {
    uint32_t u = __float_as_uint(v);
    uint32_t r = (u + 0x7fffu + ((u >> 16) & 1u)) >> 16;
    return (ushort)r;
}
static __device__ __forceinline__ float bf2f(ushort b) {
    return __uint_as_float(((uint32_t)b) << 16);
}
static __device__ __forceinline__ uint32_t fmono(float f) {
    uint32_t u = __float_as_uint(f);
    return (u & 0x80000000u) ? ~u : (u | 0x80000000u);
}
template<int N>
static __device__ __forceinline__ void waitvm() {
    if constexpr (N == 0)      asm volatile("s_waitcnt vmcnt(0)" ::: "memory");
    else if constexpr (N == 2) asm volatile("s_waitcnt vmcnt(2)" ::: "memory");
    else if constexpr (N == 3) asm volatile("s_waitcnt vmcnt(3)" ::: "memory");
    else if constexpr (N == 4) asm volatile("s_waitcnt vmcnt(4)" ::: "memory");
    else if constexpr (N == 6) asm volatile("s_waitcnt vmcnt(6)" ::: "memory");
}

// Sense-reversing grid barrier (agent scope). All NBLK blocks co-resident by
// construction (LDS 72KB -> 2/CU, launch_bounds(256,2) -> VGPR<=256).
static __device__ __forceinline__ void grid_sync(GBar* b) {
    __syncthreads();
    if (threadIdx.x == 0) {
        __threadfence();   // release our block's writes (agent scope wbL2)
        const unsigned int g =
            __hip_atomic_load(&b->gen, __ATOMIC_RELAXED, __HIP_MEMORY_SCOPE_AGENT);
        const unsigned int a =
            __hip_atomic_fetch_add(&b->cnt, 1u, __ATOMIC_ACQ_REL, __HIP_MEMORY_SCOPE_AGENT);
        if (a == NBLK - 1) {
            __hip_atomic_store(&b->cnt, 0u, __ATOMIC_RELAXED, __HIP_MEMORY_SCOPE_AGENT);
            __hip_atomic_fetch_add(&b->gen, 1u, __ATOMIC_RELEASE, __HIP_MEMORY_SCOPE_AGENT);
        } else {
            while (__hip_atomic_load(&b->gen, __ATOMIC_ACQUIRE,
                                     __HIP_MEMORY_SCOPE_AGENT) == g)
                __builtin_amdgcn_s_sleep(4);
        }
        __threadfence();   // acquire: invalidate stale L1/L2 lines
    }
    __syncthreads();
}

#define GLD16(gp, lp)                                                          \
    __builtin_amdgcn_global_load_lds(                                         \
        (const __attribute__((address_space(1))) void*)(gp),                  \
        (__attribute__((address_space(3))) void*)(lp), 16, 0, 0)

// ---------------------------------------------------------------------------
// R12's paired split-bf16 GEMM step body (verified), as a device function.
// Block (MFR*32)x(NFR*32), 4 waves (2m x 2n). Paired tiles reuse af regs
// across W_hi/W_lo subtiles; 3 rotating LDS buffers, counted-vmcnt pipeline.
// ---------------------------------------------------------------------------
template<int MFR, int NFR, int NTPX,
         int NKP, int PT1, int PO0, int PO1,
         int NKS, int ST1, int SO0, int SO1, bool GATES>
static __device__ __forceinline__ void gemm_body(
    ushort* lds, int flat,
    const ushort* __restrict__ A, int astr,
    const ushort* __restrict__ W, int kv,
    const float* __restrict__ bias,
    float* __restrict__ c,
    ushort* __restrict__ hdest, int ldh,
    const float* __restrict__ xsrc, ushort* __restrict__ xdest,
    float* __restrict__ out, int ldo,
    unsigned long long* __restrict__ keys)
{
    constexpr int ABUF = MFR * 2048;
    constexpr int WBUF = NFR * 4096;

    const int tid = threadIdx.x;
    const int lane = tid & 63;
    const int wid = tid >> 6;
    const int wm = wid >> 1, wn = wid & 1;
    const int l15 = lane & 15, lq = lane >> 4;
    const int l7 = lane & 7, l3 = lane >> 3;

    const int xcd = flat & 7, slot = flat >> 3;
    const int n_tile = xcd * NTPX + (slot % NTPX);
    const int m_tile = slot / NTPX;
    const int m0 = m_tile * (MFR * 32);
    const int n0 = n_tile * (NFR * 32);

    f32x4 acc[MFR][NFR];
#pragma unroll
    for (int m = 0; m < MFR; ++m)
#pragma unroll
        for (int n = 0; n < NFR; ++n) { f32x4 z = {0.f, 0.f, 0.f, 0.f}; acc[m][n] = z; }

    auto stageA = [&](int kcA, int bufi) {
        ushort* ab = &lds[bufi * ABUF];
#pragma unroll
        for (int i = 0; i < MFR; ++i) {
            const int rowg = (i * 4 + wid) * 8;
            const int row = rowg + l3;
            GLD16(A + (size_t)(m0 + row) * astr + kcA + ((l7 ^ (row & 7)) * 8),
                  ab + rowg * 64);
        }
    };
    auto stageP = [&](int p, int bufi) {
        stageA(p * 64 + (p < PT1 ? PO0 : PO1), bufi);
        const int kcW = p * 128;
        ushort* wb = &lds[3 * ABUF + bufi * WBUF];
#pragma unroll
        for (int i = 0; i < 2 * NFR; ++i) {      // 256B rows, 16 lanes/row
            const int rowg = (i * 4 + wid) * 4;
            const int row = rowg + lq;
            GLD16(W + (size_t)(n0 + row) * kv + kcW + ((l15 ^ (row & 15)) * 8),
                  wb + rowg * 128);
        }
    };
    auto stageS = [&](int s, int bufi) {
        stageA(s * 64 + (s < ST1 ? SO0 : SO1), bufi);
        const int kcW = NKP * 128 + s * 64;
        ushort* wb = &lds[3 * ABUF + bufi * WBUF];
#pragma unroll
        for (int i = 0; i < NFR; ++i) {          // 128B rows
            const int rowg = (i * 4 + wid) * 8;
            const int row = rowg + l3;
            GLD16(W + (size_t)(n0 + row) * kv + kcW + ((l7 ^ (row & 7)) * 8),
                  wb + rowg * 64);
        }
    };
    auto compP = [&](int bufi) {
        const ushort* ab = &lds[bufi * ABUF];
        const ushort* wb = &lds[3 * ABUF + bufi * WBUF];
#pragma unroll
        for (int kk = 0; kk < 2; ++kk) {
            short8 af[MFR];
#pragma unroll
            for (int m = 0; m < MFR; ++m) {
                const int row = wm * (MFR * 16) + m * 16 + l15;
                af[m] = *(const short8*)
                    &ab[row * 64 + (((kk * 4 + lq) ^ (row & 7)) * 8)];
            }
#pragma unroll
            for (int sub = 0; sub < 2; ++sub) {
                short8 wf[NFR];
#pragma unroll
                for (int n = 0; n < NFR; ++n) {
                    const int row = wn * (NFR * 16) + n * 16 + l15;
                    wf[n] = *(const short8*)
                        &wb[row * 128 + (((sub * 8 + kk * 4 + lq) ^ (row & 15)) * 8)];
                }
#pragma unroll
                for (int m = 0; m < MFR; ++m)
#pragma unroll
                    for (int n = 0; n < NFR; ++n)
                        acc[m][n] = __builtin_amdgcn_mfma_f32_16x16x32_bf16(
                            af[m], wf[n], acc[m][n], 0, 0, 0);
            }
        }
    };
    auto compS = [&](int bufi) {
        const ushort* ab = &lds[bufi * ABUF];
        const ushort* wb = &lds[3 * ABUF + bufi * WBUF];
#pragma unroll
        for (int kk = 0; kk < 2; ++kk) {
            short8 af[MFR], wf[NFR];
#pragma unroll
            for (int m = 0; m < MFR; ++m) {
                const int row = wm * (MFR * 16) + m * 16 + l15;
                af[m] = *(const short8*)
                    &ab[row * 64 + (((kk * 4 + lq) ^ (row & 7)) * 8)];
            }
#pragma unroll
            for (int n = 0; n < NFR; ++n) {
                const int row = wn * (NFR * 16) + n * 16 + l15;
                wf[n] = *(const short8*)
                    &wb[row * 64 + (((kk * 4 + lq) ^ (row & 7)) * 8)];
            }
#pragma unroll
            for (int m = 0; m < MFR; ++m)
#pragma unroll
                for (int n = 0; n < NFR; ++n)
                    acc[m][n] = __builtin_amdgcn_mfma_f32_16x16x32_bf16(
                        af[m], wf[n], acc[m][n], 0, 0, 0);
        }
    };

    auto STG = [&](int i, int b) { if (i < NKP) stageP(i, b); else stageS(i - NKP, b); };

    constexpr int NT = NKP + NKS;
    constexpr int GP = MFR + 2 * NFR;
    constexpr int GS = MFR + NFR;

    STG(0, 0);
    STG(1, 1);
#pragma unroll 1
    for (int i0 = 0; i0 < NT; i0 += 3) {
#pragma unroll
        for (int j = 0; j < 3; ++j) {
            const int i = i0 + j;
            if (i < NT) {
                if (i + 1 < NKP)     waitvm<GP>();
                else if (i + 1 < NT) waitvm<GS>();
                else                 waitvm<0>();
                __builtin_amdgcn_s_barrier();
                if (i + 2 < NT) STG(i + 2, (j + 2) % 3);
                if (i < NKP) compP(j); else compS(j);
            }
        }
    }

    // --- epilogue ----------------------------------------------------------
    if constexpr (GATES) {
        float* zs = (float*)&lds[0];          // 64*65*4 = 16.6 KB
        __syncthreads();
#pragma unroll
        for (int m = 0; m < MFR; ++m)
#pragma unroll
            for (int n = 0; n < NFR; ++n)
#pragma unroll
                for (int r = 0; r < 4; ++r)
                    zs[(wm * 32 + m * 16 + lq * 4 + r) * 65 +
                       wn * 32 + n * 16 + l15] = acc[m][n][r];
        __syncthreads();

        const int row = tid & 63;
        const int jl0 = (tid >> 6) * 4;
        const int grow = m0 + row;
        const int jg = n_tile * 16 + jl0;
        const f32x4 bi4 = *(const f32x4*)&bias[n0 + jl0];
        const f32x4 bf4 = *(const f32x4*)&bias[n0 + 16 + jl0];
        const f32x4 bg4 = *(const f32x4*)&bias[n0 + 32 + jl0];
        const f32x4 bo4 = *(const f32x4*)&bias[n0 + 48 + jl0];
        f32x4 cv = *(f32x4*)&c[(size_t)grow * H_SZ + jg];
        ushort hh[4], hl[4];
#pragma unroll
        for (int jj = 0; jj < 4; ++jj) {
            const float zi = zs[row * 65 + jl0 + jj] + bi4[jj];
            const float zf = zs[row * 65 + 16 + jl0 + jj] + bf4[jj];
            const float zg = zs[row * 65 + 32 + jl0 + jj] + bg4[jj];
            const float zo = zs[row * 65 + 48 + jl0 + jj] + bo4[jj];
            const float ig = 1.f / (1.f + expf(-zi));
            const float fg = 1.f / (1.f + expf(-zf));
            const float gg = tanhf(zg);
            const float og = 1.f / (1.f + expf(-zo));
            const float cn = fg * cv[jj] + ig * gg;
            cv[jj] = cn;
            const float hv = og * tanhf(cn);
            hh[jj] = f2bf(hv);
            hl[jj] = f2bf(hv - bf2f(hh[jj]));
        }
        *(f32x4*)&c[(size_t)grow * H_SZ + jg] = cv;
        ushort* hd = hdest + (size_t)grow * ldh + jg;
        uint hv2[2], lv2[2];
        hv2[0] = (uint)hh[0] | ((uint)hh[1] << 16);
        hv2[1] = (uint)hh[2] | ((uint)hh[3] << 16);
        lv2[0] = (uint)hl[0] | ((uint)hl[1] << 16);
        lv2[1] = (uint)hl[2] | ((uint)hl[3] << 16);
        *(uint*)&hd[0] = hv2[0];
        *(uint*)&hd[2] = hv2[1];
        *(uint*)&hd[1024] = lv2[0];
        *(uint*)&hd[1026] = lv2[1];            // h_lo always hi_base + 1024

        if (xdest) {                            // fused x_{t+1} conversion
            const int idx = flat * 256 + tid;   // exactly B*I = 131072
            const int b = idx >> 8, i = idx & 255;
            const float v = xsrc[(size_t)b * (T_SZ * I_SZ) + i];
            const ushort hi = f2bf(v), lo = f2bf(v - bf2f(hi));
            xdest[(size_t)b * APE + i] = hi;
            xdest[(size_t)b * APE + 256 + i] = lo;
        }
    } else {
        // MFR == NFR == 1 (32x32). Store logits; fused per-row argmax.
        float vals[4];
        const int col = n0 + wn * 16 + l15;
        const float bv = bias[col];
#pragma unroll
        for (int r = 0; r < 4; ++r) {
            const int row = m0 + wm * 16 + lq * 4 + r;
            vals[r] = acc[0][0][r] + bv;
            out[(size_t)row * ldo + col] = vals[r];
        }
        if (keys) {
            float* zs = (float*)&lds[0];        // 32*33*4 = 4.2 KB
            __syncthreads();
#pragma unroll
            for (int r = 0; r < 4; ++r)
                zs[(wm * 16 + lq * 4 + r) * 33 + wn * 16 + l15] = vals[r];
            __syncthreads();
            if (tid < 32) {
                const int row = tid;
                float best = zs[row * 33];
                int bc = 0;
#pragma unroll
                for (int cc = 1; cc < 32; ++cc) {
                    const float x = zs[row * 33 + cc];
                    if (x > best) { best = x; bc = cc; }   // strict > : earliest col
                }
                const unsigned long long key =
                    ((unsigned long long)fmono(best) << 32) |
                    (unsigned long long)(V_SZ - 1 - (n0 + bc));
                atomicMax(&keys[m0 + row], key);
            }
        }
    }
}

// ---------------------------------------------------------------------------
// Persistent encoder: 256 LSTM steps, one kernel, grid barrier between steps.
// ---------------------------------------------------------------------------
__global__ __launch_bounds__(256, 2) void enc_loop(
    ushort* __restrict__ A0, ushort* __restrict__ A1,
    const ushort* __restrict__ W, const float* __restrict__ bias,
    float* __restrict__ c, const float* __restrict__ x_hist,
    ushort* __restrict__ Adec0, GBar* __restrict__ bar)
{
    __shared__ __align__(16) ushort lds[3 * 4096 + 3 * 8192];   // 72 KB
    const int flat = blockIdx.x;
    ushort* Ab[2] = {A0, A1};
#pragma unroll 1
    for (int t = 0; t < T_SZ; ++t) {
        ushort* hdst; int ldh; const float* xs; ushort* xd;
        if (t < T_SZ - 1) {
            hdst = Ab[(t + 1) & 1] + 512; ldh = APE;
            xs = x_hist + (size_t)(t + 1) * I_SZ;
            xd = Ab[(t + 1) & 1];
        } else {
            hdst = Adec0 + 128; ldh = APD;
            xs = nullptr; xd = nullptr;
        }
        gemm_body<2, 2, 8, 20, 4, 0, 256, 20, 4, 256, 1280, true>(
            lds, flat, Ab[t & 1], APE, W, KVE, bias, c,
            hdst, ldh, xs, xd, (float*)nullptr, 0, (unsigned long long*)nullptr);
        grid_sync(bar);
    }
}

// ---------------------------------------------------------------------------
// Persistent decoder: 64 steps of {lstm -> fc+argmax -> gather}, one kernel.
// ---------------------------------------------------------------------------
__global__ __launch_bounds__(256, 2) void dec_loop(
    ushort* __restrict__ A0, ushort* __restrict__ A1,
    const ushort* __restrict__ Wd, const float* __restrict__ bpd,
    const ushort* __restrict__ Wf, const float* __restrict__ fc_b,
    float* __restrict__ c, const float* __restrict__ embed_W,
    float* __restrict__ out, unsigned long long* __restrict__ keys,
    GBar* __restrict__ bar)
{
    __shared__ __align__(16) ushort lds[3 * 4096 + 3 * 8192];   // 72 KB
    const int flat = blockIdx.x;
    ushort* Ab[2] = {A0, A1};
#pragma unroll 1
    for (int t = 0; t < FUT; ++t) {
        // LSTM step
        gemm_body<2, 2, 8, 16, 16, 128, 128, 18, 2, 0, 1024, true>(
            lds, flat, Ab[t & 1], APD, Wd, KVD, bpd, c,
            Ab[(t + 1) & 1] + 128, APD,
            (const float*)nullptr, (ushort*)nullptr,
            (float*)nullptr, 0, (unsigned long long*)nullptr);
        grid_sync(bar);
        // fc + fused argmax
        float* logits = out + (size_t)t * V_SZ;   // [B, FUT, V]
        gemm_body<1, 1, 4, 16, 16, 128, 128, 16, 16, 1152, 1152, false>(
            lds, flat, Ab[(t + 1) & 1], APD, Wf, KVF, fc_b,
            (float*)nullptr, (ushort*)nullptr, 0,
            (const float*)nullptr, (ushort*)nullptr,
            logits, FUT * V_SZ, keys);
        grid_sync(bar);
        // gather: embed argmax winner into next step's xc; reset keys
        if (flat < 16) {
            const int idx = flat * 256 + threadIdx.x;   // < 4096
            const int b = idx >> 3, e = idx & 7;
            const unsigned long long key = keys[b];
            const int yb = V_SZ - 1 - (int)(key & 0xffffffffu);
            const float v = embed_W[(size_t)yb * E_SZ + e];
            const ushort hi = f2bf(v), lo = f2bf(v - bf2f(hi));
            ushort* xd = Ab[(t + 1) & 1] + (size_t)b * APD;
            xd[e] = hi;
            xd[8 + e] = hi;
            xd[16 + e] = lo;
            if (e == 0) keys[b] = 0ull;        // after the wave's reads
        }
        grid_sync(bar);
    }
}

// ---------------------------------------------------------------------------
// Weight packing (gate-permuted rows n' = jhi*64 + g*16 + jlo), paired cols.
// ---------------------------------------------------------------------------
__global__ void pack_enc(const float* __restrict__ Wih, const float* __restrict__ Whh,
                         const float* __restrict__ b, ushort* __restrict__ Wp,
                         float* __restrict__ bp)
{
    const int k = blockIdx.x * 256 + threadIdx.x;   // < 3840
    const int np = blockIdx.y;                      // < 4096
    const int orig = ((np >> 4) & 3) * H_SZ + (np >> 6) * 16 + (np & 15);
    float v; bool lo = false;
    if (k < 2560) {                                  // paired region
        const int p = k >> 7, cc = k & 63;
        lo = (k >> 6) & 1;
        v = (p < 4) ? Wih[(size_t)orig * I_SZ + p * 64 + cc]
                    : Whh[(size_t)orig * H_SZ + (p - 4) * 64 + cc];
    } else {                                         // single region (W_hi)
        const int s = (k - 2560) >> 6, cc = k & 63;
        v = (s < 4) ? Wih[(size_t)orig * I_SZ + s * 64 + cc]
                    : Whh[(size_t)orig * H_SZ + (s - 4) * 64 + cc];
    }
    const ushort hi = f2bf(v);
    Wp[(size_t)np * KVE + k] = lo ? f2bf(v - bf2f(hi)) : hi;
    if (k == 0) bp[np] = b[orig];
}

__global__ void pack_dec(const float* __restrict__ Wih, const float* __restrict__ Whh,
                         const float* __restrict__ b, ushort* __restrict__ Wp,
                         float* __restrict__ bp)
{
    const int k = blockIdx.x * 256 + threadIdx.x;
    const int np = blockIdx.y;
    if (k >= KVD) return;                            // KVD = 3200
    const int orig = ((np >> 4) & 3) * H_SZ + (np >> 6) * 16 + (np & 15);
    float v = 0.f; bool lo = false; bool zero = false;
    if (k < 2048) {                                  // paired: Whh hi|lo
        const int p = k >> 7, cc = k & 63;
        lo = (k >> 6) & 1;
        v = Whh[(size_t)orig * H_SZ + p * 64 + cc];
    } else {
        const int s = (k - 2048) >> 6, cc = k & 63;
        if (s < 2) {                                 // xc tiles (pre-expanded)
            const int j = s * 64 + cc;
            if (j < 8)       v = Wih[(size_t)orig * E_SZ + j];
            else if (j < 16) { v = Wih[(size_t)orig * E_SZ + j - 8]; lo = true; }
            else if (j < 24) v = Wih[(size_t)orig * E_SZ + j - 16];
            else             zero = true;
        } else {                                     // h_lo singles: Whh_hi
            v = Whh[(size_t)orig * H_SZ + (s - 2) * 64 + cc];
        }
    }
    ushort w = 0;
    if (!zero) { const ushort hi = f2bf(v); w = lo ? f2bf(v - bf2f(hi)) : hi; }
    Wp[(size_t)np * KVD + k] = w;
    if (k == 0) bp[np] = b[orig];
}

__global__ void pack_fc(const float* __restrict__ W, ushort* __restrict__ Wp)
{
    const int k = blockIdx.x * 256 + threadIdx.x;   // < 3072
    const int np = blockIdx.y;                      // < 1024 (no permute)
    float v; bool lo = false;
    if (k < 2048) {
        const int p = k >> 7, cc = k & 63;
        lo = (k >> 6) & 1;
        v = W[(size_t)np * H_SZ + p * 64 + cc];
    } else {
        const int s = (k - 2048) >> 6, cc = k & 63;
        v = W[(size_t)np * H_SZ + s * 64 + cc];
    }
    const ushort hi = f2bf(v);
    Wp[(size_t)np * KVF + k] = lo ? f2bf(v - bf2f(hi)) : hi;
}

// ---------------------------------------------------------------------------
// Init: zero c + A_enc0 h region; convert x(0); xc(0) from embed row 0;
// zero dec xc pads (both buffers); zero argmax keys + barrier.
// ---------------------------------------------------------------------------
__global__ void init_all(const float* __restrict__ x0,
                         const float* __restrict__ embed_W,
                         float* __restrict__ c,
                         ushort* __restrict__ Aenc0,
                         ushort* __restrict__ Adec0,
                         ushort* __restrict__ Adec1,
                         unsigned long long* __restrict__ keys,
                         GBar* __restrict__ bar)
{
    const int idx = blockIdx.x * 256 + threadIdx.x;   // < 512*2048
    {
        const int b = idx >> 11, k = idx & 2047;
        Aenc0[(size_t)b * APE + 512 + k] = 0;
    }
    if (idx < B_SZ * H_SZ) c[idx] = 0.f;
    if (idx < B_SZ) keys[idx] = 0ull;
    if (idx == 0) { bar->cnt = 0u; bar->gen = 0u; }
    if (idx < B_SZ * I_SZ) {
        const int b = idx >> 8, i = idx & 255;
        const float v = x0[(size_t)b * (T_SZ * I_SZ) + i];
        const ushort hi = f2bf(v), lo = f2bf(v - bf2f(hi));
        Aenc0[(size_t)b * APE + i] = hi;
        Aenc0[(size_t)b * APE + 256 + i] = lo;
    }
    if (idx < B_SZ * 104) {
        const int b = idx / 104, col = 24 + idx % 104;
        Adec0[(size_t)b * APD + col] = 0;
        Adec1[(size_t)b * APD + col] = 0;
    }
    if (idx < B_SZ * 24) {
        const int b = idx / 24, col = idx % 24;
        float v;
        if (col < 8)       v = embed_W[col];
        else if (col < 16) v = embed_W[col - 8];
        else               v = embed_W[col - 16];
        const ushort hi = f2bf(v);
        Adec0[(size_t)b * APD + col] = (col < 16) ? hi : f2bf(v - bf2f(hi));
    }
}

extern "C" void kernel_launch(void* const* d_in, const int* in_sizes, int n_in,
                              void* d_out, int out_size, void* d_ws, size_t ws_size,
                              hipStream_t stream)
{
    const float* x_hist  = (const float*)d_in[0];
    const float* enc_Wih = (const float*)d_in[1];
    const float* enc_Whh = (const float*)d_in[2];
    const float* enc_b   = (const float*)d_in[3];
    const float* embed_W = (const float*)d_in[4];
    const float* dec_Wih = (const float*)d_in[5];
    const float* dec_Whh = (const float*)d_in[6];
    const float* dec_b   = (const float*)d_in[7];
    const float* fc_W    = (const float*)d_in[8];
    const float* fc_b    = (const float*)d_in[9];
    float* out = (float*)d_out;

    char* p = (char*)d_ws;
    auto alloc = [&](size_t bytes) {
        char* r = p;
        p += (bytes + 255) & ~(size_t)255;
        return r;
    };
    ushort* W_enc  = (ushort*)alloc((size_t)4096 * KVE * 2);   // 30 MB
    ushort* W_dec  = (ushort*)alloc((size_t)4096 * KVD * 2);   // 25 MB
    ushort* W_fc   = (ushort*)alloc((size_t)1024 * KVF * 2);   // 6 MB
    ushort* A_enc0 = (ushort*)alloc((size_t)B_SZ * APE * 2);   // 2.5 MB
    ushort* A_enc1 = (ushort*)alloc((size_t)B_SZ * APE * 2);
    ushort* A_dec0 = (ushort*)alloc((size_t)B_SZ * APD * 2);   // 2.13 MB
    ushort* A_dec1 = (ushort*)alloc((size_t)B_SZ * APD * 2);
    float*  cbuf   = (float*)alloc((size_t)B_SZ * H_SZ * 4);   // 2 MB
    float*  bpe    = (float*)alloc(4096 * 4);
    float*  bpd    = (float*)alloc(4096 * 4);
    unsigned long long* keys = (unsigned long long*)alloc(B_SZ * 8);
    GBar*   bar    = (GBar*)alloc(256);

    const dim3 blk(256);
    hipLaunchKernelGGL(pack_enc, dim3(15, 4096), blk, 0, stream, enc_Wih, enc_Whh, enc_b, W_enc, bpe);
    hipLaunchKernelGGL(pack_dec, dim3(13, 4096), blk, 0, stream, dec_Wih, dec_Whh, dec_b, W_dec, bpd);
    hipLaunchKernelGGL(pack_fc,  dim3(12, 1024), blk, 0, stream, fc_W, W_fc);
    hipLaunchKernelGGL(init_all, dim3(4096), blk, 0, stream, x_hist, embed_W, cbuf,
                       A_enc0, A_dec0, A_dec1, keys, bar);

    hipLaunchKernelGGL(enc_loop, dim3(NBLK), blk, 0, stream,
                       A_enc0, A_enc1, W_enc, bpe, cbuf, x_hist, A_dec0, bar);

    hipLaunchKernelGGL(dec_loop, dim3(NBLK), blk, 0, stream,
                       A_dec0, A_dec1, W_dec, bpd, W_fc, fc_b, cbuf,
                       embed_W, out, keys, bar);
}

// Round 14
// 9832.494 us; speedup vs baseline: 4.7784x; 4.7784x over previous
//
#include <hip/hip_runtime.h>
#include <cmath>

typedef __attribute__((ext_vector_type(8))) short short8;
typedef __attribute__((ext_vector_type(4))) float f32x4;

#define B_SZ 512
#define T_SZ 256
#define I_SZ 256
#define H_SZ 1024
#define V_SZ 1024
#define E_SZ 8
#define FUT 64

// R5 numerics (3 products: A_hi*W_hi + A_hi*W_lo + A_lo*W_hi), paired layout:
// A phys (unchanged):
//   enc: [x_hi 256 | x_lo 256 | h_hi 1024 | h_lo 1024] = 2560
//   dec: [xc 128 (x_hi8|x_hi8|x_lo8|0) | h_hi 1024 | h_lo 1024] = 2176
// W packed, two regions:
//   paired: per hi-A-seg p (64 cols): [W_hi(seg p) 64 | W_lo(seg p) 64]
//   single: per lo-A-seg s: [W_hi(seg s) 64]   (+ dec xc pre-expanded tiles)
//   W_enc = 20*128 + 20*64 = 3840 ; W_dec = 16*128 + 18*64 = 3200 ;
//   W_fc  = 16*128 + 16*64 = 3072
#define KVE 3840
#define KVD 3200
#define KVF 3072
#define APE 2560
#define APD 2176

static __device__ __forceinline__ ushort f2bf(float v) {
    uint32_t u = __float_as_uint(v);
    uint32_t r = (u + 0x7fffu + ((u >> 16) & 1u)) >> 16;
    return (ushort)r;
}
static __device__ __forceinline__ float bf2f(ushort b) {
    return __uint_as_float(((uint32_t)b) << 16);
}
// Monotone float->uint mapping: a > b  <=>  map(a) > map(b) (finite floats).
static __device__ __forceinline__ uint32_t fmono(float f) {
    uint32_t u = __float_as_uint(f);
    return (u & 0x80000000u) ? ~u : (u | 0x80000000u);
}
template<int N>
static __device__ __forceinline__ void waitvm() {
    if constexpr (N == 0)      asm volatile("s_waitcnt vmcnt(0)" ::: "memory");
    else if constexpr (N == 2) asm volatile("s_waitcnt vmcnt(2)" ::: "memory");
    else if constexpr (N == 3) asm volatile("s_waitcnt vmcnt(3)" ::: "memory");
    else if constexpr (N == 4) asm volatile("s_waitcnt vmcnt(4)" ::: "memory");
    else if constexpr (N == 6) asm volatile("s_waitcnt vmcnt(6)" ::: "memory");
}

#define GLD16(gp, lp)                                                          \
    __builtin_amdgcn_global_load_lds(                                         \
        (const __attribute__((address_space(1))) void*)(gp),                  \
        (__attribute__((address_space(3))) void*)(lp), 16, 0, 0)

// ---------------------------------------------------------------------------
// Paired split-bf16 GEMM step. Block (MFR*32) x (NFR*32), 4 waves (2m x 2n).
// Two compile-time phases:
//   paired tiles p<NKP : stage A-seg (64 cols) once + W-pair (128 cols);
//     compute reuses af registers across both W subtiles (hi, lo).
//   single tiles s<NKS : stage A-seg + W (64 cols) as before.
// 3 rotating buffers, counted-vmcnt pipeline (stage i+2 while computing i;
// wait = gld-count of stage i+1: GP = MFR+2*NFR, GS = MFR+NFR; per-wave
// counts identical across waves so vmcnt + s_barrier is sound).
// LDS rows: A/W-single 128B rows (8 slots, XOR row&7); W-pair 256B rows
// (16 slots, XOR row&15); global source pre-swizzled, ds_read same XOR.
// ---------------------------------------------------------------------------
template<int MFR, int NFR, int NTPX,
         int NKP, int PT1, int PO0, int PO1,
         int NKS, int ST1, int SO0, int SO1, bool GATES>
__global__ __launch_bounds__(256) void gemm_step(
    const ushort* __restrict__ A, int astr,
    const ushort* __restrict__ W, int kv,
    const float* __restrict__ bias,
    float* __restrict__ c,
    ushort* __restrict__ hdest, int ldh,
    const float* __restrict__ xsrc, ushort* __restrict__ xdest,
    float* __restrict__ out, int ldo,
    unsigned long long* __restrict__ keys)
{
    constexpr int ABUF = MFR * 2048;             // ushorts per A buffer
    constexpr int WBUF = NFR * 4096;             // ushorts per W buffer (pair-size)
    __shared__ __align__(16) ushort lds[3 * ABUF + 3 * WBUF];

    const int tid = threadIdx.x;
    const int lane = tid & 63;
    const int wid = tid >> 6;
    const int wm = wid >> 1, wn = wid & 1;
    const int l15 = lane & 15, lq = lane >> 4;
    const int l7 = lane & 7, l3 = lane >> 3;

    const int flat = blockIdx.x;
    const int xcd = flat & 7, slot = flat >> 3;
    const int n_tile = xcd * NTPX + (slot % NTPX);
    const int m_tile = slot / NTPX;
    const int m0 = m_tile * (MFR * 32);
    const int n0 = n_tile * (NFR * 32);

    f32x4 acc[MFR][NFR];
#pragma unroll
    for (int m = 0; m < MFR; ++m)
#pragma unroll
        for (int n = 0; n < NFR; ++n) { f32x4 z = {0.f, 0.f, 0.f, 0.f}; acc[m][n] = z; }

    auto stageA = [&](int kcA, int bufi) {
        ushort* ab = &lds[bufi * ABUF];
#pragma unroll
        for (int i = 0; i < MFR; ++i) {
            const int rowg = (i * 4 + wid) * 8;
            const int row = rowg + l3;
            GLD16(A + (size_t)(m0 + row) * astr + kcA + ((l7 ^ (row & 7)) * 8),
                  ab + rowg * 64);
        }
    };
    auto stageP = [&](int p, int bufi) {
        stageA(p * 64 + (p < PT1 ? PO0 : PO1), bufi);
        const int kcW = p * 128;
        ushort* wb = &lds[3 * ABUF + bufi * WBUF];
#pragma unroll
        for (int i = 0; i < 2 * NFR; ++i) {      // 256B rows, 16 lanes/row
            const int rowg = (i * 4 + wid) * 4;
            const int row = rowg + lq;
            GLD16(W + (size_t)(n0 + row) * kv + kcW + ((l15 ^ (row & 15)) * 8),
                  wb + rowg * 128);
        }
    };
    auto stageS = [&](int s, int bufi) {
        stageA(s * 64 + (s < ST1 ? SO0 : SO1), bufi);
        const int kcW = NKP * 128 + s * 64;
        ushort* wb = &lds[3 * ABUF + bufi * WBUF];
#pragma unroll
        for (int i = 0; i < NFR; ++i) {          // 128B rows
            const int rowg = (i * 4 + wid) * 8;
            const int row = rowg + l3;
            GLD16(W + (size_t)(n0 + row) * kv + kcW + ((l7 ^ (row & 7)) * 8),
                  wb + rowg * 64);
        }
    };
    auto compP = [&](int bufi) {
        const ushort* ab = &lds[bufi * ABUF];
        const ushort* wb = &lds[3 * ABUF + bufi * WBUF];
#pragma unroll
        for (int kk = 0; kk < 2; ++kk) {
            short8 af[MFR];
#pragma unroll
            for (int m = 0; m < MFR; ++m) {
                const int row = wm * (MFR * 16) + m * 16 + l15;
                af[m] = *(const short8*)
                    &ab[row * 64 + (((kk * 4 + lq) ^ (row & 7)) * 8)];
            }
#pragma unroll
            for (int sub = 0; sub < 2; ++sub) {
                short8 wf[NFR];
#pragma unroll
                for (int n = 0; n < NFR; ++n) {
                    const int row = wn * (NFR * 16) + n * 16 + l15;
                    wf[n] = *(const short8*)
                        &wb[row * 128 + (((sub * 8 + kk * 4 + lq) ^ (row & 15)) * 8)];
                }
#pragma unroll
                for (int m = 0; m < MFR; ++m)
#pragma unroll
                    for (int n = 0; n < NFR; ++n)
                        acc[m][n] = __builtin_amdgcn_mfma_f32_16x16x32_bf16(
                            af[m], wf[n], acc[m][n], 0, 0, 0);
            }
        }
    };
    auto compS = [&](int bufi) {
        const ushort* ab = &lds[bufi * ABUF];
        const ushort* wb = &lds[3 * ABUF + bufi * WBUF];
#pragma unroll
        for (int kk = 0; kk < 2; ++kk) {
            short8 af[MFR], wf[NFR];
#pragma unroll
            for (int m = 0; m < MFR; ++m) {
                const int row = wm * (MFR * 16) + m * 16 + l15;
                af[m] = *(const short8*)
                    &ab[row * 64 + (((kk * 4 + lq) ^ (row & 7)) * 8)];
            }
#pragma unroll
            for (int n = 0; n < NFR; ++n) {
                const int row = wn * (NFR * 16) + n * 16 + l15;
                wf[n] = *(const short8*)
                    &wb[row * 64 + (((kk * 4 + lq) ^ (row & 7)) * 8)];
            }
#pragma unroll
            for (int m = 0; m < MFR; ++m)
#pragma unroll
                for (int n = 0; n < NFR; ++n)
                    acc[m][n] = __builtin_amdgcn_mfma_f32_16x16x32_bf16(
                        af[m], wf[n], acc[m][n], 0, 0, 0);
        }
    };

    auto STG = [&](int i, int b) { if (i < NKP) stageP(i, b); else stageS(i - NKP, b); };

    constexpr int NT = NKP + NKS;
    constexpr int GP = MFR + 2 * NFR;            // gld/wave of a paired stage
    constexpr int GS = MFR + NFR;                // gld/wave of a single stage

    STG(0, 0);
    STG(1, 1);
#pragma unroll 1
    for (int i0 = 0; i0 < NT; i0 += 3) {
#pragma unroll
        for (int j = 0; j < 3; ++j) {
            const int i = i0 + j;
            if (i < NT) {
                // wait: stage i complete; outstanding = stage i+1 only.
                if (i + 1 < NKP)     waitvm<GP>();
                else if (i + 1 < NT) waitvm<GS>();
                else                 waitvm<0>();
                __builtin_amdgcn_s_barrier();
                if (i + 2 < NT) STG(i + 2, (j + 2) % 3);
                if (i < NKP) compP(j); else compS(j);
            }
        }
    }

    // --- epilogue ----------------------------------------------------------
    if constexpr (GATES) {
        // MFR == NFR == 2 (64x64 tile). Exchange acc via LDS z-tile.
        float* zs = (float*)&lds[0];          // 64*65*4 = 16.6 KB
        __syncthreads();
#pragma unroll
        for (int m = 0; m < MFR; ++m)
#pragma unroll
            for (int n = 0; n < NFR; ++n)
#pragma unroll
                for (int r = 0; r < 4; ++r)
                    zs[(wm * 32 + m * 16 + lq * 4 + r) * 65 +
                       wn * 32 + n * 16 + l15] = acc[m][n][r];
        __syncthreads();

        const int row = tid & 63;
        const int jl0 = (tid >> 6) * 4;
        const int grow = m0 + row;
        const int jg = n_tile * 16 + jl0;
        const f32x4 bi4 = *(const f32x4*)&bias[n0 + jl0];
        const f32x4 bf4 = *(const f32x4*)&bias[n0 + 16 + jl0];
        const f32x4 bg4 = *(const f32x4*)&bias[n0 + 32 + jl0];
        const f32x4 bo4 = *(const f32x4*)&bias[n0 + 48 + jl0];
        f32x4 cv = *(f32x4*)&c[(size_t)grow * H_SZ + jg];
        ushort hh[4], hl[4];
#pragma unroll
        for (int jj = 0; jj < 4; ++jj) {
            const float zi = zs[row * 65 + jl0 + jj] + bi4[jj];
            const float zf = zs[row * 65 + 16 + jl0 + jj] + bf4[jj];
            const float zg = zs[row * 65 + 32 + jl0 + jj] + bg4[jj];
            const float zo = zs[row * 65 + 48 + jl0 + jj] + bo4[jj];
            const float ig = 1.f / (1.f + expf(-zi));
            const float fg = 1.f / (1.f + expf(-zf));
            const float gg = tanhf(zg);
            const float og = 1.f / (1.f + expf(-zo));
            const float cn = fg * cv[jj] + ig * gg;
            cv[jj] = cn;
            const float hv = og * tanhf(cn);
            hh[jj] = f2bf(hv);
            hl[jj] = f2bf(hv - bf2f(hh[jj]));
        }
        *(f32x4*)&c[(size_t)grow * H_SZ + jg] = cv;
        ushort* hd = hdest + (size_t)grow * ldh + jg;
        uint hv2[2], lv2[2];
        hv2[0] = (uint)hh[0] | ((uint)hh[1] << 16);
        hv2[1] = (uint)hh[2] | ((uint)hh[3] << 16);
        lv2[0] = (uint)hl[0] | ((uint)hl[1] << 16);
        lv2[1] = (uint)hl[2] | ((uint)hl[3] << 16);
        *(uint*)&hd[0] = hv2[0];
        *(uint*)&hd[2] = hv2[1];
        *(uint*)&hd[1024] = lv2[0];
        *(uint*)&hd[1026] = lv2[1];            // h_lo always hi_base + 1024

        if (xdest) {                            // fused x_{t+1} conversion
            const int idx = flat * 256 + tid;   // exactly B*I = 131072
            const int b = idx >> 8, i = idx & 255;
            const float v = xsrc[(size_t)b * (T_SZ * I_SZ) + i];
            const ushort hi = f2bf(v), lo = f2bf(v - bf2f(hi));
            xdest[(size_t)b * APE + i] = hi;
            xdest[(size_t)b * APE + 256 + i] = lo;
        }
    } else {
        // MFR == NFR == 1 (32x32). Store logits; fused per-row argmax.
        float vals[4];
        const int col = n0 + wn * 16 + l15;
        const float bv = bias[col];
#pragma unroll
        for (int r = 0; r < 4; ++r) {
            const int row = m0 + wm * 16 + lq * 4 + r;
            vals[r] = acc[0][0][r] + bv;
            out[(size_t)row * ldo + col] = vals[r];
        }
        if (keys) {
            float* zs = (float*)&lds[0];        // 32*33*4 = 4.2 KB
            __syncthreads();
#pragma unroll
            for (int r = 0; r < 4; ++r)
                zs[(wm * 16 + lq * 4 + r) * 33 + wn * 16 + l15] = vals[r];
            __syncthreads();
            if (tid < 32) {
                const int row = tid;
                float best = zs[row * 33];
                int bc = 0;
#pragma unroll
                for (int cc = 1; cc < 32; ++cc) {
                    const float x = zs[row * 33 + cc];
                    if (x > best) { best = x; bc = cc; }   // strict > : earliest col
                }
                const unsigned long long key =
                    ((unsigned long long)fmono(best) << 32) |
                    (unsigned long long)(V_SZ - 1 - (n0 + bc));
                atomicMax(&keys[m0 + row], key);
            }
        }
    }
}

// ---------------------------------------------------------------------------
// Gather: read per-row argmax key -> embed row -> xc of next dec A buffer;
// reset key to 0 for the next step (same-wave read-before-write).
// ---------------------------------------------------------------------------
__global__ __launch_bounds__(256) void gather_embed(
    unsigned long long* __restrict__ keys,
    const float* __restrict__ embed_W,
    ushort* __restrict__ xdest)
{
    const int idx = blockIdx.x * 256 + threadIdx.x;   // < 4096
    const int b = idx >> 3, e = idx & 7;
    const unsigned long long key = keys[b];
    const int yb = V_SZ - 1 - (int)(key & 0xffffffffu);
    const float v = embed_W[(size_t)yb * E_SZ + e];
    const ushort hi = f2bf(v), lo = f2bf(v - bf2f(hi));
    ushort* xd = xdest + (size_t)b * APD;
    xd[e] = hi;
    xd[8 + e] = hi;
    xd[16 + e] = lo;
    if (e == 0) keys[b] = 0ull;                 // after the wave's reads
}

// ---------------------------------------------------------------------------
// Weight packing (gate-permuted rows n' = jhi*64 + g*16 + jlo), paired cols.
// ---------------------------------------------------------------------------
__global__ void pack_enc(const float* __restrict__ Wih, const float* __restrict__ Whh,
                         const float* __restrict__ b, ushort* __restrict__ Wp,
                         float* __restrict__ bp)
{
    const int k = blockIdx.x * 256 + threadIdx.x;   // < 3840
    const int np = blockIdx.y;                      // < 4096
    const int orig = ((np >> 4) & 3) * H_SZ + (np >> 6) * 16 + (np & 15);
    float v; bool lo = false;
    if (k < 2560) {                                  // paired region
        const int p = k >> 7, cc = k & 63;
        lo = (k >> 6) & 1;
        v = (p < 4) ? Wih[(size_t)orig * I_SZ + p * 64 + cc]
                    : Whh[(size_t)orig * H_SZ + (p - 4) * 64 + cc];
    } else {                                         // single region (W_hi)
        const int s = (k - 2560) >> 6, cc = k & 63;
        v = (s < 4) ? Wih[(size_t)orig * I_SZ + s * 64 + cc]
                    : Whh[(size_t)orig * H_SZ + (s - 4) * 64 + cc];
    }
    const ushort hi = f2bf(v);
    Wp[(size_t)np * KVE + k] = lo ? f2bf(v - bf2f(hi)) : hi;
    if (k == 0) bp[np] = b[orig];
}

__global__ void pack_dec(const float* __restrict__ Wih, const float* __restrict__ Whh,
                         const float* __restrict__ b, ushort* __restrict__ Wp,
                         float* __restrict__ bp)
{
    const int k = blockIdx.x * 256 + threadIdx.x;
    const int np = blockIdx.y;
    if (k >= KVD) return;                            // KVD = 3200
    const int orig = ((np >> 4) & 3) * H_SZ + (np >> 6) * 16 + (np & 15);
    float v = 0.f; bool lo = false; bool zero = false;
    if (k < 2048) {                                  // paired: Whh hi|lo
        const int p = k >> 7, cc = k & 63;
        lo = (k >> 6) & 1;
        v = Whh[(size_t)orig * H_SZ + p * 64 + cc];
    } else {
        const int s = (k - 2048) >> 6, cc = k & 63;
        if (s < 2) {                                 // xc tiles (pre-expanded)
            const int j = s * 64 + cc;
            if (j < 8)       v = Wih[(size_t)orig * E_SZ + j];
            else if (j < 16) { v = Wih[(size_t)orig * E_SZ + j - 8]; lo = true; }
            else if (j < 24) v = Wih[(size_t)orig * E_SZ + j - 16];
            else             zero = true;
        } else {                                     // h_lo singles: Whh_hi
            v = Whh[(size_t)orig * H_SZ + (s - 2) * 64 + cc];
        }
    }
    ushort w = 0;
    if (!zero) { const ushort hi = f2bf(v); w = lo ? f2bf(v - bf2f(hi)) : hi; }
    Wp[(size_t)np * KVD + k] = w;
    if (k == 0) bp[np] = b[orig];
}

__global__ void pack_fc(const float* __restrict__ W, ushort* __restrict__ Wp)
{
    const int k = blockIdx.x * 256 + threadIdx.x;   // < 3072
    const int np = blockIdx.y;                      // < 1024 (no permute)
    float v; bool lo = false;
    if (k < 2048) {
        const int p = k >> 7, cc = k & 63;
        lo = (k >> 6) & 1;
        v = W[(size_t)np * H_SZ + p * 64 + cc];
    } else {
        const int s = (k - 2048) >> 6, cc = k & 63;
        v = W[(size_t)np * H_SZ + s * 64 + cc];
    }
    const ushort hi = f2bf(v);
    Wp[(size_t)np * KVF + k] = lo ? f2bf(v - bf2f(hi)) : hi;
}

// ---------------------------------------------------------------------------
// Init: zero c + A_enc0 h region; convert x(0); xc(0) from embed row 0;
// zero dec xc pads (both buffers); zero argmax keys.
// ---------------------------------------------------------------------------
__global__ void init_all(const float* __restrict__ x0,
                         const float* __restrict__ embed_W,
                         float* __restrict__ c,
                         ushort* __restrict__ Aenc0,
                         ushort* __restrict__ Adec0,
                         ushort* __restrict__ Adec1,
                         unsigned long long* __restrict__ keys)
{
    const int idx = blockIdx.x * 256 + threadIdx.x;   // < 512*2048
    {
        const int b = idx >> 11, k = idx & 2047;
        Aenc0[(size_t)b * APE + 512 + k] = 0;
    }
    if (idx < B_SZ * H_SZ) c[idx] = 0.f;
    if (idx < B_SZ) keys[idx] = 0ull;
    if (idx < B_SZ * I_SZ) {
        const int b = idx >> 8, i = idx & 255;
        const float v = x0[(size_t)b * (T_SZ * I_SZ) + i];
        const ushort hi = f2bf(v), lo = f2bf(v - bf2f(hi));
        Aenc0[(size_t)b * APE + i] = hi;
        Aenc0[(size_t)b * APE + 256 + i] = lo;
    }
    if (idx < B_SZ * 104) {
        const int b = idx / 104, col = 24 + idx % 104;
        Adec0[(size_t)b * APD + col] = 0;
        Adec1[(size_t)b * APD + col] = 0;
    }
    if (idx < B_SZ * 24) {
        const int b = idx / 24, col = idx % 24;
        float v;
        if (col < 8)       v = embed_W[col];
        else if (col < 16) v = embed_W[col - 8];
        else               v = embed_W[col - 16];
        const ushort hi = f2bf(v);
        Adec0[(size_t)b * APD + col] = (col < 16) ? hi : f2bf(v - bf2f(hi));
    }
}

extern "C" void kernel_launch(void* const* d_in, const int* in_sizes, int n_in,
                              void* d_out, int out_size, void* d_ws, size_t ws_size,
                              hipStream_t stream)
{
    const float* x_hist  = (const float*)d_in[0];
    const float* enc_Wih = (const float*)d_in[1];
    const float* enc_Whh = (const float*)d_in[2];
    const float* enc_b   = (const float*)d_in[3];
    const float* embed_W = (const float*)d_in[4];
    const float* dec_Wih = (const float*)d_in[5];
    const float* dec_Whh = (const float*)d_in[6];
    const float* dec_b   = (const float*)d_in[7];
    const float* fc_W    = (const float*)d_in[8];
    const float* fc_b    = (const float*)d_in[9];
    float* out = (float*)d_out;

    char* p = (char*)d_ws;
    auto alloc = [&](size_t bytes) {
        char* r = p;
        p += (bytes + 255) & ~(size_t)255;
        return r;
    };
    ushort* W_enc  = (ushort*)alloc((size_t)4096 * KVE * 2);   // 30 MB
    ushort* W_dec  = (ushort*)alloc((size_t)4096 * KVD * 2);   // 25 MB
    ushort* W_fc   = (ushort*)alloc((size_t)1024 * KVF * 2);   // 6 MB
    ushort* A_enc0 = (ushort*)alloc((size_t)B_SZ * APE * 2);   // 2.5 MB
    ushort* A_enc1 = (ushort*)alloc((size_t)B_SZ * APE * 2);
    ushort* A_dec0 = (ushort*)alloc((size_t)B_SZ * APD * 2);   // 2.13 MB
    ushort* A_dec1 = (ushort*)alloc((size_t)B_SZ * APD * 2);
    float*  cbuf   = (float*)alloc((size_t)B_SZ * H_SZ * 4);   // 2 MB
    float*  bpe    = (float*)alloc(4096 * 4);
    float*  bpd    = (float*)alloc(4096 * 4);
    unsigned long long* keys = (unsigned long long*)alloc(B_SZ * 8);

    const dim3 blk(256);
    hipLaunchKernelGGL(pack_enc, dim3(15, 4096), blk, 0, stream, enc_Wih, enc_Whh, enc_b, W_enc, bpe);
    hipLaunchKernelGGL(pack_dec, dim3(13, 4096), blk, 0, stream, dec_Wih, dec_Whh, dec_b, W_dec, bpd);
    hipLaunchKernelGGL(pack_fc,  dim3(12, 1024), blk, 0, stream, fc_W, W_fc);
    hipLaunchKernelGGL(init_all, dim3(4096), blk, 0, stream, x_hist, embed_W, cbuf, A_enc0, A_dec0, A_dec1, keys);

    ushort* Ae[2] = {A_enc0, A_enc1};
    ushort* Ad[2] = {A_dec0, A_dec1};

    // Encoder. Paired p: A col = 64p + (p<4 ? 0 : 256)  [x_hi, h_hi]
    //          Single s: A col = 64s + (s<4 ? 256 : 1280) [x_lo, h_lo]
    for (int t = 0; t < T_SZ; ++t) {
        ushort* hdst; int ldh; const float* xs; ushort* xd;
        if (t < T_SZ - 1) {
            hdst = Ae[(t + 1) & 1] + 512; ldh = APE;
            xs = x_hist + (size_t)(t + 1) * I_SZ;
            xd = Ae[(t + 1) & 1];
        } else {
            hdst = Ad[0] + 128; ldh = APD;
            xs = nullptr; xd = nullptr;
        }
        hipLaunchKernelGGL((gemm_step<2, 2, 8, 20, 4, 0, 256, 20, 4, 256, 1280, true>),
                           dim3(512), blk, 0, stream,
                           Ae[t & 1], APE, W_enc, KVE, bpe, cbuf,
                           hdst, ldh, xs, xd, (float*)nullptr, 0,
                           (unsigned long long*)nullptr);
    }

    // Decoder. Paired p: A col = 64p + 128 [h_hi].
    //          Single s: A col = 64s + (s<2 ? 0 : 1024) [xc, h_lo].
    // fc:      Paired p: A col = 64p + 128 [h_hi]; Single s: 64s + 1152 [h_lo].
    for (int t = 0; t < FUT; ++t) {
        hipLaunchKernelGGL((gemm_step<2, 2, 8, 16, 16, 128, 128, 18, 2, 0, 1024, true>),
                           dim3(512), blk, 0, stream,
                           Ad[t & 1], APD, W_dec, KVD, bpd, cbuf,
                           Ad[(t + 1) & 1] + 128, APD,
                           (const float*)nullptr, (ushort*)nullptr,
                           (float*)nullptr, 0,
                           (unsigned long long*)nullptr);
        float* logits = out + (size_t)t * V_SZ;   // [B, FUT, V]
        hipLaunchKernelGGL((gemm_step<1, 1, 4, 16, 16, 128, 128, 16, 16, 1152, 1152, false>),
                           dim3(512), blk, 0, stream,
                           Ad[(t + 1) & 1], APD, W_fc, KVF, fc_b,
                           (float*)nullptr, (ushort*)nullptr, 0,
                           (const float*)nullptr, (ushort*)nullptr,
                           logits, FUT * V_SZ, keys);
        hipLaunchKernelGGL(gather_embed, dim3(16), blk, 0, stream,
                           keys, embed_W, Ad[(t + 1) & 1]);
    }
}